// Round 1
// baseline (407.366 us; speedup 1.0000x reference)
//
#include <hip/hip_runtime.h>

#define N_NODES 50000
#define N_EDGES 800000
#define F_IN    512
#define F_HID   64
#define F_OUT   16
#define NT      (N_NODES / 16)      // 3125 row tiles
#define GRID    1024                // mega blocks: 4 per CU

#define SCAN_B  1024
#define SCAN_NB ((N_NODES + SCAN_B - 1) / SCAN_B)   // 49

typedef short bf16x8 __attribute__((ext_vector_type(8)));
typedef float f32x4  __attribute__((ext_vector_type(4)));

__device__ __forceinline__ short bhi_of(float v) {
    return (short)(__float_as_uint(v) >> 16);
}
__device__ __forceinline__ short blo_of(float v) {
    float hif = __uint_as_float(__float_as_uint(v) & 0xffff0000u);
    return (short)(__float_as_uint(v - hif) >> 16);
}

// ---------------- mega: all blocks count a histogram slice, then GEMM1 -------
// GEMM1: 8 waves, wave w owns K slice [64w,64w+64); B frags built from W1 once,
// register-persistent; block grid-strides over 16-row tiles with A prefetch.
// grid=1024 -> 4 blocks/CU co-resident (LDS 34816*4=136KB, VGPR<=64 via
// launch_bounds(512,8)) so barrier stalls in one block hide under another.
__global__ __launch_bounds__(512, 8) void k_mega(const float* __restrict__ x,
                                                 const float* __restrict__ W1,
                                                 const int* __restrict__ dst,
                                                 int* __restrict__ count,
                                                 float* __restrict__ h) {
    // ---- histogram slice (uniform across all blocks; ~1.5 edges/thread) ----
    for (int e = blockIdx.x * 512 + threadIdx.x; e < N_EDGES; e += GRID * 512)
        atomicAdd(&count[dst[e]], 1);

    // ---- gemm1 ----
    __shared__ float red[8][64][17];
    const int gb   = blockIdx.x;
    const int wave = threadIdx.x >> 6;
    const int lane = threadIdx.x & 63;
    const int m = lane & 15, q = lane >> 4;

    // build this wave's B fragments from W1 (once per block lifetime)
    bf16x8 Bh[2][4], Bl[2][4];
#pragma unroll
    for (int si = 0; si < 2; ++si) {
        const int s = wave * 2 + si;
#pragma unroll
        for (int t = 0; t < 4; ++t)
#pragma unroll
            for (int j = 0; j < 8; ++j) {
                float w = W1[(size_t)(s * 32 + q * 8 + j) * F_HID + t * 16 + m];
                Bh[si][t][j] = bhi_of(w);
                Bl[si][t][j] = blo_of(w);
            }
    }

    int tile = gb;
    f32x4 a0[2], a1[2];
    {
        const float* xr = x + (size_t)(tile * 16 + m) * F_IN + q * 8;
#pragma unroll
        for (int si = 0; si < 2; ++si) {
            const int s = wave * 2 + si;
            a0[si] = *(const f32x4*)(xr + s * 32);
            a1[si] = *(const f32x4*)(xr + s * 32 + 4);
        }
    }

    while (true) {
        const int next = tile + GRID;
        f32x4 n0[2], n1[2];
        if (next < NT) {
            const float* xr = x + (size_t)(next * 16 + m) * F_IN + q * 8;
#pragma unroll
            for (int si = 0; si < 2; ++si) {
                const int s = wave * 2 + si;
                n0[si] = *(const f32x4*)(xr + s * 32);
                n1[si] = *(const f32x4*)(xr + s * 32 + 4);
            }
        }

        f32x4 acc[4] = {f32x4{0,0,0,0}, f32x4{0,0,0,0}, f32x4{0,0,0,0}, f32x4{0,0,0,0}};
#pragma unroll
        for (int si = 0; si < 2; ++si) {
            bf16x8 ahi, alo;
#pragma unroll
            for (int j = 0; j < 8; ++j) {
                float v = (j < 4) ? a0[si][j] : a1[si][j - 4];
                ahi[j] = bhi_of(v);
                alo[j] = blo_of(v);
            }
#pragma unroll
            for (int t = 0; t < 4; ++t) {
                acc[t] = __builtin_amdgcn_mfma_f32_16x16x32_bf16(ahi, Bh[si][t], acc[t], 0, 0, 0);
                acc[t] = __builtin_amdgcn_mfma_f32_16x16x32_bf16(alo, Bh[si][t], acc[t], 0, 0, 0);
                acc[t] = __builtin_amdgcn_mfma_f32_16x16x32_bf16(ahi, Bl[si][t], acc[t], 0, 0, 0);
            }
        }

#pragma unroll
        for (int t = 0; t < 4; ++t)
#pragma unroll
            for (int r = 0; r < 4; ++r)
                red[wave][lane][t * 4 + r] = acc[t][r];
        __syncthreads();
        const int r0 = tile * 16;
        for (int f = threadIdx.x; f < 16 * 64; f += 512) {
            int row = f >> 6, col = f & 63;
            int ln  = (col & 15) + 16 * (row >> 2);
            int idx = (col >> 4) * 4 + (row & 3);
            float v = red[0][ln][idx] + red[1][ln][idx] + red[2][ln][idx] + red[3][ln][idx]
                    + red[4][ln][idx] + red[5][ln][idx] + red[6][ln][idx] + red[7][ln][idx];
            h[(size_t)(r0 + row) * F_HID + col] = v;
        }
        if (next >= NT) break;
        __syncthreads();
#pragma unroll
        for (int si = 0; si < 2; ++si) { a0[si] = n0[si]; a1[si] = n1[si]; }
        tile = next;
    }
}

// ---------------- scanA: block-local exclusive scan + dinv --------------------
__global__ __launch_bounds__(SCAN_B) void k_scanA(const int* __restrict__ count,
                                                  int* __restrict__ offs,
                                                  int* __restrict__ bsum,
                                                  float* __restrict__ dinv) {
    __shared__ int s[SCAN_B];
    int t = threadIdx.x;
    int i = blockIdx.x * SCAN_B + t;
    int v = (i < N_NODES) ? count[i] : 0;
    s[t] = v;
    __syncthreads();
    for (int off = 1; off < SCAN_B; off <<= 1) {
        int u = (t >= off) ? s[t - off] : 0;
        __syncthreads();
        s[t] += u;
        __syncthreads();
    }
    if (i < N_NODES) {
        offs[i] = s[t] - v;
        dinv[i] = rsqrtf((float)(v + 1));
    }
    if (t == SCAN_B - 1) bsum[blockIdx.x] = s[t];
}

// ---------------- scanBC: per-block redundant reduce of block sums ------------
__global__ __launch_bounds__(SCAN_B) void k_scanBC(int* __restrict__ offs,
                                                   const int* __restrict__ bsum) {
    __shared__ int base;
    if (threadIdx.x < 64) {
        int v = ((int)threadIdx.x < (int)blockIdx.x) ? bsum[threadIdx.x] : 0;
        for (int d = 1; d < 64; d <<= 1) v += __shfl_xor(v, d);
        if (threadIdx.x == 0) base = v;
    }
    __syncthreads();
    int i = blockIdx.x * SCAN_B + threadIdx.x;
    if (i < N_NODES) offs[i] += base;
    if (i == 0) offs[N_NODES] = N_EDGES;
}

// ---------------- fill: atomicSub on degree array claims slots ----------------
__global__ void k_fill(const int* __restrict__ src, const int* __restrict__ dst,
                       const int* __restrict__ offs, int* __restrict__ count,
                       const float* __restrict__ dinv,
                       int* __restrict__ src_sorted, float* __restrict__ w_sorted) {
    int e = blockIdx.x * blockDim.x + threadIdx.x;
    if (e < N_EDGES) {
        int d = dst[e];
        int s = src[e];
        int pos = atomicSub(&count[d], 1) - 1;
        int slot = offs[d] + pos;
        src_sorted[slot] = s;
        w_sorted[slot] = dinv[s] * dinv[d];
    }
}

// ---------------- CSR aggregation F=64: unroll-8, 4 acc chains ----------------
__global__ __launch_bounds__(256) void k_agg64_csr(const int* __restrict__ offs,
                                                   const int* __restrict__ srcs,
                                                   const float* __restrict__ wgt,
                                                   const float* __restrict__ dinv,
                                                   const float* __restrict__ h,
                                                   const float* __restrict__ b1,
                                                   float* __restrict__ h1) {
    int node = blockIdx.x * 4 + (threadIdx.x >> 6);
    int j = threadIdx.x & 63;
    if (node >= N_NODES) return;
    float dn = dinv[node];
    float acc0 = h[(size_t)node * F_HID + j] * dn * dn;
    float acc1 = 0.0f, acc2 = 0.0f, acc3 = 0.0f;
    int k0 = offs[node], k1 = offs[node + 1];
    int k = k0;
    for (; k + 8 <= k1; k += 8) {
        int s0 = srcs[k],     s1 = srcs[k + 1], s2 = srcs[k + 2], s3 = srcs[k + 3];
        int s4 = srcs[k + 4], s5 = srcs[k + 5], s6 = srcs[k + 6], s7 = srcs[k + 7];
        float w0 = wgt[k],     w1 = wgt[k + 1], w2 = wgt[k + 2], w3 = wgt[k + 3];
        float w4 = wgt[k + 4], w5 = wgt[k + 5], w6 = wgt[k + 6], w7 = wgt[k + 7];
        float v0 = h[(size_t)s0 * F_HID + j];
        float v1 = h[(size_t)s1 * F_HID + j];
        float v2 = h[(size_t)s2 * F_HID + j];
        float v3 = h[(size_t)s3 * F_HID + j];
        float v4 = h[(size_t)s4 * F_HID + j];
        float v5 = h[(size_t)s5 * F_HID + j];
        float v6 = h[(size_t)s6 * F_HID + j];
        float v7 = h[(size_t)s7 * F_HID + j];
        acc0 = fmaf(v0, w0, acc0);
        acc1 = fmaf(v1, w1, acc1);
        acc2 = fmaf(v2, w2, acc2);
        acc3 = fmaf(v3, w3, acc3);
        acc0 = fmaf(v4, w4, acc0);
        acc1 = fmaf(v5, w5, acc1);
        acc2 = fmaf(v6, w6, acc2);
        acc3 = fmaf(v7, w7, acc3);
    }
    for (; k < k1; ++k)
        acc0 = fmaf(h[(size_t)srcs[k] * F_HID + j], wgt[k], acc0);
    h1[(size_t)node * F_HID + j] = fmaxf((acc0 + acc1) + (acc2 + acc3) + b1[j], 0.0f);
}

// ---------------- GEMM2: h1[N,64] @ W2[64,16] -> h2[N,16] ----------------
__global__ void k_gemm2(const float* __restrict__ h1, const float* __restrict__ W,
                        float* __restrict__ h2) {
    int t = blockIdx.x * blockDim.x + threadIdx.x;
    if (t < N_NODES * F_OUT) {
        int i = t >> 4, j = t & 15;
        float acc = 0.0f;
#pragma unroll
        for (int k = 0; k < F_HID; ++k)
            acc = fmaf(h1[(size_t)i * F_HID + k], W[k * F_OUT + j], acc);
        h2[t] = acc;
    }
}

// ---------------- CSR aggregation F=16: 4 groups x 16 feats, unroll-4 ---------
__global__ __launch_bounds__(256) void k_agg16_csr(const int* __restrict__ offs,
                                                   const int* __restrict__ srcs,
                                                   const float* __restrict__ wgt,
                                                   const float* __restrict__ dinv,
                                                   const float* __restrict__ h2,
                                                   const float* __restrict__ b2,
                                                   float* __restrict__ out) {
    int node = blockIdx.x * 4 + (threadIdx.x >> 6);
    int lane = threadIdx.x & 63;
    int eo = lane >> 4;
    int j  = lane & 15;
    if (node >= N_NODES) return;
    float dn = dinv[node];
    float acc0 = 0.0f, acc1 = 0.0f, acc2 = 0.0f, acc3 = 0.0f;
    int k0 = offs[node], k1 = offs[node + 1];
    int k = k0 + eo;
    for (; k + 12 < k1; k += 16) {
        int s0 = srcs[k], s1 = srcs[k + 4], s2 = srcs[k + 8], s3 = srcs[k + 12];
        float w0 = wgt[k], w1 = wgt[k + 4], w2 = wgt[k + 8], w3 = wgt[k + 12];
        float v0 = h2[(size_t)s0 * F_OUT + j];
        float v1 = h2[(size_t)s1 * F_OUT + j];
        float v2 = h2[(size_t)s2 * F_OUT + j];
        float v3 = h2[(size_t)s3 * F_OUT + j];
        acc0 = fmaf(v0, w0, acc0);
        acc1 = fmaf(v1, w1, acc1);
        acc2 = fmaf(v2, w2, acc2);
        acc3 = fmaf(v3, w3, acc3);
    }
    for (; k < k1; k += 4)
        acc0 = fmaf(h2[(size_t)srcs[k] * F_OUT + j], wgt[k], acc0);
    float acc = (acc0 + acc1) + (acc2 + acc3);
    acc += __shfl_xor(acc, 16);
    acc += __shfl_xor(acc, 32);
    if (eo == 0)
        out[(size_t)node * F_OUT + j] =
            acc + h2[(size_t)node * F_OUT + j] * dn * dn + b2[j];
}

extern "C" void kernel_launch(void* const* d_in, const int* in_sizes, int n_in,
                              void* d_out, int out_size, void* d_ws, size_t ws_size,
                              hipStream_t stream) {
    const float* x  = (const float*)d_in[0];
    const int*   ei = (const int*)d_in[1];
    const float* W1 = (const float*)d_in[2];
    const float* b1 = (const float*)d_in[3];
    const float* W2 = (const float*)d_in[4];
    const float* b2 = (const float*)d_in[5];
    float* out = (float*)d_out;

    const int* src = ei;
    const int* dst = ei + N_EDGES;

    int* wsi = (int*)d_ws;
    int* count      = wsi;                  // 50176 (consumed to 0 by k_fill)
    int* offs       = count + 50176;        // 50304
    int* bsum       = offs + 50304;         // 64
    int* src_sorted = bsum + 64;            // 800000
    float* w_sorted = (float*)(src_sorted + N_EDGES);    // 800000
    float* dinv = w_sorted + N_EDGES;                    // 50176
    float* h    = dinv + 50176;                          // N*64
    float* h1   = h + (size_t)N_NODES * F_HID;           // N*64
    float* h2   = h;                                     // alias: h dead after agg64

    (void)hipMemsetAsync(count, 0, N_NODES * sizeof(int), stream);

    // gemm1 + degree histogram in one launch (uniform across all blocks)
    k_mega<<<GRID, 512, 0, stream>>>(x, W1, dst, count, h);

    k_scanA<<<SCAN_NB, SCAN_B, 0, stream>>>(count, offs, bsum, dinv);
    k_scanBC<<<SCAN_NB, SCAN_B, 0, stream>>>(offs, bsum);
    k_fill<<<(N_EDGES + 255) / 256, 256, 0, stream>>>(src, dst, offs, count, dinv,
                                                      src_sorted, w_sorted);

    k_agg64_csr<<<(N_NODES + 3) / 4, 256, 0, stream>>>(offs, src_sorted, w_sorted,
                                                       dinv, h, b1, h1);
    k_gemm2<<<(N_NODES * F_OUT + 255) / 256, 256, 0, stream>>>(h1, W2, h2);
    k_agg16_csr<<<(N_NODES + 3) / 4, 256, 0, stream>>>(offs, src_sorted, w_sorted,
                                                       dinv, h2, b2, out);
}

// Round 2
// 325.548 us; speedup vs baseline: 1.2513x; 1.2513x over previous
//
#include <hip/hip_runtime.h>

#define N_NODES 50000
#define N_EDGES 800000
#define F_IN    512
#define F_HID   64
#define F_OUT   16
#define NT      (N_NODES / 16)      // 3125 row tiles
#define GRID    512                 // mega blocks (2/CU; reg ceiling ~128 incl AGPR)

#define SCAN_B  1024
#define SCAN_NB ((N_NODES + SCAN_B - 1) / SCAN_B)   // 49

typedef short bf16x8 __attribute__((ext_vector_type(8)));
typedef float f32x4  __attribute__((ext_vector_type(4)));

__device__ __forceinline__ short bhi_of(float v) {
    return (short)(__float_as_uint(v) >> 16);
}
__device__ __forceinline__ short blo_of(float v) {
    float hif = __uint_as_float(__float_as_uint(v) & 0xffff0000u);
    return (short)(__float_as_uint(v - hif) >> 16);
}

// ---------------- mega: all blocks count a histogram slice, then GEMM1 -------
// GEMM1: 8 waves, wave w owns K slice [64w,64w+64); B frags built from W1 once,
// register-persistent (lives in AGPRs; total regs ~128 -> 2 blocks/CU).
// NOTE: do NOT add a min-waves launch_bounds arg — unified VGPR+AGPR file means
// a 64-reg cap forces acc/B-frag spills to scratch (round-1: +330MB HBM, 2x dur).
// red is double-buffered (pad 20 keeps ds_*_b128 16B-aligned & bank-conflict-free)
// -> ONE barrier per tile; waves 4-7 run ahead into next tile's MFMA while
// waves 0-3 do the vectorized b128 reduce of the previous buffer.
__global__ __launch_bounds__(512) void k_mega(const float* __restrict__ x,
                                              const float* __restrict__ W1,
                                              const int* __restrict__ dst,
                                              int* __restrict__ count,
                                              float* __restrict__ h) {
    // ---- histogram slice (uniform across all blocks; ~3 edges/thread) ----
    for (int e = blockIdx.x * 512 + threadIdx.x; e < N_EDGES; e += GRID * 512)
        atomicAdd(&count[dst[e]], 1);

    // ---- gemm1 ----
    __shared__ float red[2][8][64][20];   // 81920 B = exactly 2 blocks/CU
    const int wave = threadIdx.x >> 6;
    const int lane = threadIdx.x & 63;
    const int m = lane & 15, q = lane >> 4;

    // build this wave's B fragments from W1 (once per block lifetime)
    bf16x8 Bh[2][4], Bl[2][4];
#pragma unroll
    for (int si = 0; si < 2; ++si) {
        const int s = wave * 2 + si;
#pragma unroll
        for (int t = 0; t < 4; ++t)
#pragma unroll
            for (int j = 0; j < 8; ++j) {
                float w = W1[(size_t)(s * 32 + q * 8 + j) * F_HID + t * 16 + m];
                Bh[si][t][j] = bhi_of(w);
                Bl[si][t][j] = blo_of(w);
            }
    }

    int tile = blockIdx.x;
    f32x4 a0[2], a1[2];
    {
        const float* xr = x + (size_t)(tile * 16 + m) * F_IN + q * 8;
#pragma unroll
        for (int si = 0; si < 2; ++si) {
            const int s = wave * 2 + si;
            a0[si] = *(const f32x4*)(xr + s * 32);
            a1[si] = *(const f32x4*)(xr + s * 32 + 4);
        }
    }

    int p = 0;
    while (true) {
        const int next = tile + GRID;
        f32x4 n0[2], n1[2];
        if (next < NT) {
            const float* xr = x + (size_t)(next * 16 + m) * F_IN + q * 8;
#pragma unroll
            for (int si = 0; si < 2; ++si) {
                const int s = wave * 2 + si;
                n0[si] = *(const f32x4*)(xr + s * 32);
                n1[si] = *(const f32x4*)(xr + s * 32 + 4);
            }
        }

        f32x4 acc[4] = {f32x4{0,0,0,0}, f32x4{0,0,0,0}, f32x4{0,0,0,0}, f32x4{0,0,0,0}};
#pragma unroll
        for (int si = 0; si < 2; ++si) {
            bf16x8 ahi, alo;
#pragma unroll
            for (int j = 0; j < 8; ++j) {
                float v = (j < 4) ? a0[si][j] : a1[si][j - 4];
                ahi[j] = bhi_of(v);
                alo[j] = blo_of(v);
            }
#pragma unroll
            for (int t = 0; t < 4; ++t) {
                acc[t] = __builtin_amdgcn_mfma_f32_16x16x32_bf16(ahi, Bh[si][t], acc[t], 0, 0, 0);
                acc[t] = __builtin_amdgcn_mfma_f32_16x16x32_bf16(alo, Bh[si][t], acc[t], 0, 0, 0);
                acc[t] = __builtin_amdgcn_mfma_f32_16x16x32_bf16(ahi, Bl[si][t], acc[t], 0, 0, 0);
            }
        }

        // vectorized partial write: 4x ds_write_b128 (stride 20 f32 -> 16B aligned)
#pragma unroll
        for (int t = 0; t < 4; ++t)
            *(f32x4*)&red[p][wave][lane][t * 4] = acc[t];
        __syncthreads();   // the ONLY barrier per tile (red is double-buffered)

        const int r0 = tile * 16;
        if (threadIdx.x < 256) {   // waves 0-3 reduce; waves 4-7 run ahead
            const int c  = threadIdx.x & 63;
            const int rg = threadIdx.x >> 6;
            const int ln = (c & 15) + 16 * rg;
            const int ib = (c >> 4) * 4;
            f32x4 s = *(const f32x4*)&red[p][0][ln][ib];
#pragma unroll
            for (int w = 1; w < 8; ++w)
                s += *(const f32x4*)&red[p][w][ln][ib];
#pragma unroll
            for (int a = 0; a < 4; ++a)
                h[(size_t)(r0 + rg * 4 + a) * F_HID + c] = s[a];
        }
        if (next >= NT) break;
#pragma unroll
        for (int si = 0; si < 2; ++si) { a0[si] = n0[si]; a1[si] = n1[si]; }
        tile = next;
        p ^= 1;
    }
}

// ---------------- scanA: block-local exclusive scan + dinv --------------------
__global__ __launch_bounds__(SCAN_B) void k_scanA(const int* __restrict__ count,
                                                  int* __restrict__ offs,
                                                  int* __restrict__ bsum,
                                                  float* __restrict__ dinv) {
    __shared__ int s[SCAN_B];
    int t = threadIdx.x;
    int i = blockIdx.x * SCAN_B + t;
    int v = (i < N_NODES) ? count[i] : 0;
    s[t] = v;
    __syncthreads();
    for (int off = 1; off < SCAN_B; off <<= 1) {
        int u = (t >= off) ? s[t - off] : 0;
        __syncthreads();
        s[t] += u;
        __syncthreads();
    }
    if (i < N_NODES) {
        offs[i] = s[t] - v;
        dinv[i] = rsqrtf((float)(v + 1));
    }
    if (t == SCAN_B - 1) bsum[blockIdx.x] = s[t];
}

// ---------------- scanBC: per-block redundant reduce of block sums ------------
__global__ __launch_bounds__(SCAN_B) void k_scanBC(int* __restrict__ offs,
                                                   const int* __restrict__ bsum) {
    __shared__ int base;
    if (threadIdx.x < 64) {
        int v = ((int)threadIdx.x < (int)blockIdx.x) ? bsum[threadIdx.x] : 0;
        for (int d = 1; d < 64; d <<= 1) v += __shfl_xor(v, d);
        if (threadIdx.x == 0) base = v;
    }
    __syncthreads();
    int i = blockIdx.x * SCAN_B + threadIdx.x;
    if (i < N_NODES) offs[i] += base;
    if (i == 0) offs[N_NODES] = N_EDGES;
}

// ---------------- fill: atomicSub on degree array claims slots ----------------
__global__ void k_fill(const int* __restrict__ src, const int* __restrict__ dst,
                       const int* __restrict__ offs, int* __restrict__ count,
                       const float* __restrict__ dinv,
                       int* __restrict__ src_sorted, float* __restrict__ w_sorted) {
    int e = blockIdx.x * blockDim.x + threadIdx.x;
    if (e < N_EDGES) {
        int d = dst[e];
        int s = src[e];
        int pos = atomicSub(&count[d], 1) - 1;
        int slot = offs[d] + pos;
        src_sorted[slot] = s;
        w_sorted[slot] = dinv[s] * dinv[d];
    }
}

// ---------------- CSR aggregation F=64: unroll-8, 4 acc chains ----------------
__global__ __launch_bounds__(256) void k_agg64_csr(const int* __restrict__ offs,
                                                   const int* __restrict__ srcs,
                                                   const float* __restrict__ wgt,
                                                   const float* __restrict__ dinv,
                                                   const float* __restrict__ h,
                                                   const float* __restrict__ b1,
                                                   float* __restrict__ h1) {
    int node = blockIdx.x * 4 + (threadIdx.x >> 6);
    int j = threadIdx.x & 63;
    if (node >= N_NODES) return;
    float dn = dinv[node];
    float acc0 = h[(size_t)node * F_HID + j] * dn * dn;
    float acc1 = 0.0f, acc2 = 0.0f, acc3 = 0.0f;
    int k0 = offs[node], k1 = offs[node + 1];
    int k = k0;
    for (; k + 8 <= k1; k += 8) {
        int s0 = srcs[k],     s1 = srcs[k + 1], s2 = srcs[k + 2], s3 = srcs[k + 3];
        int s4 = srcs[k + 4], s5 = srcs[k + 5], s6 = srcs[k + 6], s7 = srcs[k + 7];
        float w0 = wgt[k],     w1 = wgt[k + 1], w2 = wgt[k + 2], w3 = wgt[k + 3];
        float w4 = wgt[k + 4], w5 = wgt[k + 5], w6 = wgt[k + 6], w7 = wgt[k + 7];
        float v0 = h[(size_t)s0 * F_HID + j];
        float v1 = h[(size_t)s1 * F_HID + j];
        float v2 = h[(size_t)s2 * F_HID + j];
        float v3 = h[(size_t)s3 * F_HID + j];
        float v4 = h[(size_t)s4 * F_HID + j];
        float v5 = h[(size_t)s5 * F_HID + j];
        float v6 = h[(size_t)s6 * F_HID + j];
        float v7 = h[(size_t)s7 * F_HID + j];
        acc0 = fmaf(v0, w0, acc0);
        acc1 = fmaf(v1, w1, acc1);
        acc2 = fmaf(v2, w2, acc2);
        acc3 = fmaf(v3, w3, acc3);
        acc0 = fmaf(v4, w4, acc0);
        acc1 = fmaf(v5, w5, acc1);
        acc2 = fmaf(v6, w6, acc2);
        acc3 = fmaf(v7, w7, acc3);
    }
    for (; k < k1; ++k)
        acc0 = fmaf(h[(size_t)srcs[k] * F_HID + j], wgt[k], acc0);
    h1[(size_t)node * F_HID + j] = fmaxf((acc0 + acc1) + (acc2 + acc3) + b1[j], 0.0f);
}

// ---------------- GEMM2: h1[N,64] @ W2[64,16] -> h2[N,16] ----------------
__global__ void k_gemm2(const float* __restrict__ h1, const float* __restrict__ W,
                        float* __restrict__ h2) {
    int t = blockIdx.x * blockDim.x + threadIdx.x;
    if (t < N_NODES * F_OUT) {
        int i = t >> 4, j = t & 15;
        float acc = 0.0f;
#pragma unroll
        for (int k = 0; k < F_HID; ++k)
            acc = fmaf(h1[(size_t)i * F_HID + k], W[k * F_OUT + j], acc);
        h2[t] = acc;
    }
}

// ---------------- CSR aggregation F=16: 4 groups x 16 feats, unroll-4 ---------
__global__ __launch_bounds__(256) void k_agg16_csr(const int* __restrict__ offs,
                                                   const int* __restrict__ srcs,
                                                   const float* __restrict__ wgt,
                                                   const float* __restrict__ dinv,
                                                   const float* __restrict__ h2,
                                                   const float* __restrict__ b2,
                                                   float* __restrict__ out) {
    int node = blockIdx.x * 4 + (threadIdx.x >> 6);
    int lane = threadIdx.x & 63;
    int eo = lane >> 4;
    int j  = lane & 15;
    if (node >= N_NODES) return;
    float dn = dinv[node];
    float acc0 = 0.0f, acc1 = 0.0f, acc2 = 0.0f, acc3 = 0.0f;
    int k0 = offs[node], k1 = offs[node + 1];
    int k = k0 + eo;
    for (; k + 12 < k1; k += 16) {
        int s0 = srcs[k], s1 = srcs[k + 4], s2 = srcs[k + 8], s3 = srcs[k + 12];
        float w0 = wgt[k], w1 = wgt[k + 4], w2 = wgt[k + 8], w3 = wgt[k + 12];
        float v0 = h2[(size_t)s0 * F_OUT + j];
        float v1 = h2[(size_t)s1 * F_OUT + j];
        float v2 = h2[(size_t)s2 * F_OUT + j];
        float v3 = h2[(size_t)s3 * F_OUT + j];
        acc0 = fmaf(v0, w0, acc0);
        acc1 = fmaf(v1, w1, acc1);
        acc2 = fmaf(v2, w2, acc2);
        acc3 = fmaf(v3, w3, acc3);
    }
    for (; k < k1; k += 4)
        acc0 = fmaf(h2[(size_t)srcs[k] * F_OUT + j], wgt[k], acc0);
    float acc = (acc0 + acc1) + (acc2 + acc3);
    acc += __shfl_xor(acc, 16);
    acc += __shfl_xor(acc, 32);
    if (eo == 0)
        out[(size_t)node * F_OUT + j] =
            acc + h2[(size_t)node * F_OUT + j] * dn * dn + b2[j];
}

extern "C" void kernel_launch(void* const* d_in, const int* in_sizes, int n_in,
                              void* d_out, int out_size, void* d_ws, size_t ws_size,
                              hipStream_t stream) {
    const float* x  = (const float*)d_in[0];
    const int*   ei = (const int*)d_in[1];
    const float* W1 = (const float*)d_in[2];
    const float* b1 = (const float*)d_in[3];
    const float* W2 = (const float*)d_in[4];
    const float* b2 = (const float*)d_in[5];
    float* out = (float*)d_out;

    const int* src = ei;
    const int* dst = ei + N_EDGES;

    int* wsi = (int*)d_ws;
    int* count      = wsi;                  // 50176 (consumed to 0 by k_fill)
    int* offs       = count + 50176;        // 50304
    int* bsum       = offs + 50304;         // 64
    int* src_sorted = bsum + 64;            // 800000
    float* w_sorted = (float*)(src_sorted + N_EDGES);    // 800000
    float* dinv = w_sorted + N_EDGES;                    // 50176
    float* h    = dinv + 50176;                          // N*64
    float* h1   = h + (size_t)N_NODES * F_HID;           // N*64
    float* h2   = h;                                     // alias: h dead after agg64

    (void)hipMemsetAsync(count, 0, N_NODES * sizeof(int), stream);

    // gemm1 + degree histogram in one launch (uniform across all blocks)
    k_mega<<<GRID, 512, 0, stream>>>(x, W1, dst, count, h);

    k_scanA<<<SCAN_NB, SCAN_B, 0, stream>>>(count, offs, bsum, dinv);
    k_scanBC<<<SCAN_NB, SCAN_B, 0, stream>>>(offs, bsum);
    k_fill<<<(N_EDGES + 255) / 256, 256, 0, stream>>>(src, dst, offs, count, dinv,
                                                      src_sorted, w_sorted);

    k_agg64_csr<<<(N_NODES + 3) / 4, 256, 0, stream>>>(offs, src_sorted, w_sorted,
                                                       dinv, h, b1, h1);
    k_gemm2<<<(N_NODES * F_OUT + 255) / 256, 256, 0, stream>>>(h1, W2, h2);
    k_agg16_csr<<<(N_NODES + 3) / 4, 256, 0, stream>>>(offs, src_sorted, w_sorted,
                                                       dinv, h2, b2, out);
}

// Round 3
// 317.955 us; speedup vs baseline: 1.2812x; 1.0239x over previous
//
#include <hip/hip_runtime.h>

#define N_NODES 50000
#define N_EDGES 800000
#define F_IN    512
#define F_HID   64
#define F_OUT   16
#define NT      (N_NODES / 16)      // 3125 row tiles
#define GRID    512                 // mega blocks (2/CU; LDS 74KB, reg ~128 incl AGPR)

#define SCAN_B  1024
#define SCAN_NB ((N_NODES + SCAN_B - 1) / SCAN_B)   // 49

typedef short bf16x8 __attribute__((ext_vector_type(8)));
typedef float f32x4  __attribute__((ext_vector_type(4)));

__device__ __forceinline__ short bhi_of(float v) {
    return (short)(__float_as_uint(v) >> 16);
}
__device__ __forceinline__ short blo_of(float v) {
    float hif = __uint_as_float(__float_as_uint(v) & 0xffff0000u);
    return (short)(__float_as_uint(v - hif) >> 16);
}

// ---------------- mega: all blocks count a histogram slice, then GEMM1 -------
// GEMM1 v3: x was previously read as 128B chunks at 2KB stride (16-row register
// gather) -> ~1.27 TB/s DRAM efficiency, latency-bound. Now each block stages
// its 32KB A-tile through LDS with fully CONTIGUOUS 1KB-per-wave-instr global
// loads (T14 issue-early/write-late), XOR-swizzled LDS (byte ^ ((row&7)<<4),
// write side + read side) so fragment ds_read_b128 is bank-conflict-free.
// Wave split: kw = wave>>2 picks K half [kw*256,+256), cg = wave&3 picks output
// cols [cg*16,+16). 2-way reduction via tiny red buffer (vs old 8-way/40KB).
// One barrier per tile; Abuf and red double-buffered.
// NOTE: no min-waves launch_bounds — unified VGPR+AGPR file; a 64-reg cap
// spilled acc/B-frags in round-1 (+330MB HBM, 2x dur).
__global__ __launch_bounds__(512) void k_mega(const float* __restrict__ x,
                                              const float* __restrict__ W1,
                                              const int* __restrict__ dst,
                                              int* __restrict__ count,
                                              float* __restrict__ h) {
    // ---- histogram slice (uniform across all blocks; ~3 edges/thread) ----
    for (int e = blockIdx.x * 512 + threadIdx.x; e < N_EDGES; e += GRID * 512)
        atomicAdd(&count[dst[e]], 1);

    // ---- gemm1 ----
    __shared__ __align__(16) float Abuf[2][8192];        // 2 x 32KB A-tile
    __shared__ float red[2][4][16][17];                  // 2 x 4.25KB partials
    const int wave = threadIdx.x >> 6;
    const int lane = threadIdx.x & 63;
    const int m  = lane & 15, q = lane >> 4;
    const int kw = wave >> 2;        // K half
    const int cg = wave & 3;         // output col group

    // build this wave's B fragments from W1 (once per block lifetime):
    // 8 K-steps of 32 within half kw, cols cg*16..+16. 16 x bf16x8 = 64 VGPR.
    bf16x8 Bh[8], Bl[8];
#pragma unroll
    for (int s = 0; s < 8; ++s)
#pragma unroll
        for (int j = 0; j < 8; ++j) {
            float w = W1[(size_t)((kw * 8 + s) * 32 + q * 8 + j) * F_HID + cg * 16 + m];
            Bh[s][j] = bhi_of(w);
            Bl[s][j] = blo_of(w);
        }

    // ---- prologue: stage tile0 (contiguous 1KB per wave-instr, swz write) ----
    int tile = blockIdx.x;
    {
        const char* gb = (const char*)(x + (size_t)tile * 16 * F_IN);
        char* lb = (char*)&Abuf[0][0];
#pragma unroll
        for (int i = 0; i < 4; ++i) {
            const int c = wave * 4 + i;
            const int o = c * 1024 + lane * 16;
            const int sw = ((c >> 1) & 7) << 4;          // row = o>>11 = c>>1
            *(f32x4*)(lb + (o ^ sw)) = *(const f32x4*)(gb + o);
        }
    }
    __syncthreads();

    int p = 0;
    const int swr = (m & 7) << 4;    // read-side swizzle (row = m)
    while (true) {
        const int next = tile + GRID;

        // (1) issue next tile's global loads early (contiguous), write late
        f32x4 v[4];
        if (next < NT) {
            const char* gb = (const char*)(x + (size_t)next * 16 * F_IN);
#pragma unroll
            for (int i = 0; i < 4; ++i) {
                const int o = (wave * 4 + i) * 1024 + lane * 16;
                v[i] = *(const f32x4*)(gb + o);
            }
        }

        // (2) fragments from Abuf[p] + MFMA (2 acc chains)
        f32x4 accA = {0, 0, 0, 0}, accB = {0, 0, 0, 0};
        const char* ab = (const char*)&Abuf[p][0];
#pragma unroll
        for (int s = 0; s < 8; ++s) {
            const int abase = m * 2048 + kw * 1024 + s * 128 + q * 32;
            f32x4 x0 = *(const f32x4*)(ab + (abase ^ swr));
            f32x4 x1 = *(const f32x4*)(ab + ((abase + 16) ^ swr));
            bf16x8 ahi, alo;
#pragma unroll
            for (int j = 0; j < 4; ++j) {
                ahi[j] = bhi_of(x0[j]);  alo[j] = blo_of(x0[j]);
                ahi[j + 4] = bhi_of(x1[j]);  alo[j + 4] = blo_of(x1[j]);
            }
            if (s & 1) {
                accB = __builtin_amdgcn_mfma_f32_16x16x32_bf16(ahi, Bh[s], accB, 0, 0, 0);
                accB = __builtin_amdgcn_mfma_f32_16x16x32_bf16(alo, Bh[s], accB, 0, 0, 0);
                accB = __builtin_amdgcn_mfma_f32_16x16x32_bf16(ahi, Bl[s], accB, 0, 0, 0);
            } else {
                accA = __builtin_amdgcn_mfma_f32_16x16x32_bf16(ahi, Bh[s], accA, 0, 0, 0);
                accA = __builtin_amdgcn_mfma_f32_16x16x32_bf16(alo, Bh[s], accA, 0, 0, 0);
                accA = __builtin_amdgcn_mfma_f32_16x16x32_bf16(ahi, Bl[s], accA, 0, 0, 0);
            }
        }
        f32x4 acc = accA + accB;

        // (3) write next tile into Abuf[p^1] (readers of p^1 finished before
        //     last barrier; new readers come after the next barrier)
        if (next < NT) {
            char* lb = (char*)&Abuf[p ^ 1][0];
#pragma unroll
            for (int i = 0; i < 4; ++i) {
                const int c = wave * 4 + i;
                const int o = c * 1024 + lane * 16;
                const int sw = ((c >> 1) & 7) << 4;
                *(f32x4*)(lb + (o ^ sw)) = v[i];
            }
        }

        // (4) 2-way K reduction: kw=1 publishes partials
        if (kw == 1) {
#pragma unroll
            for (int r = 0; r < 4; ++r)
                red[p][cg][q * 4 + r][m] = acc[r];
        }
        __syncthreads();   // the only barrier per tile

        // (5) kw=0 combines + stores 16x16 block at cols cg*16..+16
        if (kw == 0) {
            const int r0 = tile * 16;
#pragma unroll
            for (int r = 0; r < 4; ++r)
                h[(size_t)(r0 + q * 4 + r) * F_HID + cg * 16 + m] =
                    acc[r] + red[p][cg][q * 4 + r][m];
        }
        if (next >= NT) break;
        tile = next;
        p ^= 1;
    }
}

// ---------------- scanA: block-local exclusive scan + dinv --------------------
__global__ __launch_bounds__(SCAN_B) void k_scanA(const int* __restrict__ count,
                                                  int* __restrict__ offs,
                                                  int* __restrict__ bsum,
                                                  float* __restrict__ dinv) {
    __shared__ int s[SCAN_B];
    int t = threadIdx.x;
    int i = blockIdx.x * SCAN_B + t;
    int v = (i < N_NODES) ? count[i] : 0;
    s[t] = v;
    __syncthreads();
    for (int off = 1; off < SCAN_B; off <<= 1) {
        int u = (t >= off) ? s[t - off] : 0;
        __syncthreads();
        s[t] += u;
        __syncthreads();
    }
    if (i < N_NODES) {
        offs[i] = s[t] - v;
        dinv[i] = rsqrtf((float)(v + 1));
    }
    if (t == SCAN_B - 1) bsum[blockIdx.x] = s[t];
}

// ---------------- scanBC: per-block redundant reduce of block sums ------------
__global__ __launch_bounds__(SCAN_B) void k_scanBC(int* __restrict__ offs,
                                                   const int* __restrict__ bsum) {
    __shared__ int base;
    if (threadIdx.x < 64) {
        int v = ((int)threadIdx.x < (int)blockIdx.x) ? bsum[threadIdx.x] : 0;
        for (int d = 1; d < 64; d <<= 1) v += __shfl_xor(v, d);
        if (threadIdx.x == 0) base = v;
    }
    __syncthreads();
    int i = blockIdx.x * SCAN_B + threadIdx.x;
    if (i < N_NODES) offs[i] += base;
    if (i == 0) offs[N_NODES] = N_EDGES;
}

// ---------------- fill: atomicSub on degree array claims slots ----------------
__global__ void k_fill(const int* __restrict__ src, const int* __restrict__ dst,
                       const int* __restrict__ offs, int* __restrict__ count,
                       const float* __restrict__ dinv,
                       int* __restrict__ src_sorted, float* __restrict__ w_sorted) {
    int e = blockIdx.x * blockDim.x + threadIdx.x;
    if (e < N_EDGES) {
        int d = dst[e];
        int s = src[e];
        int pos = atomicSub(&count[d], 1) - 1;
        int slot = offs[d] + pos;
        src_sorted[slot] = s;
        w_sorted[slot] = dinv[s] * dinv[d];
    }
}

// ---------------- CSR aggregation F=64: unroll-8, 4 acc chains ----------------
__global__ __launch_bounds__(256) void k_agg64_csr(const int* __restrict__ offs,
                                                   const int* __restrict__ srcs,
                                                   const float* __restrict__ wgt,
                                                   const float* __restrict__ dinv,
                                                   const float* __restrict__ h,
                                                   const float* __restrict__ b1,
                                                   float* __restrict__ h1) {
    int node = blockIdx.x * 4 + (threadIdx.x >> 6);
    int j = threadIdx.x & 63;
    if (node >= N_NODES) return;
    float dn = dinv[node];
    float acc0 = h[(size_t)node * F_HID + j] * dn * dn;
    float acc1 = 0.0f, acc2 = 0.0f, acc3 = 0.0f;
    int k0 = offs[node], k1 = offs[node + 1];
    int k = k0;
    for (; k + 8 <= k1; k += 8) {
        int s0 = srcs[k],     s1 = srcs[k + 1], s2 = srcs[k + 2], s3 = srcs[k + 3];
        int s4 = srcs[k + 4], s5 = srcs[k + 5], s6 = srcs[k + 6], s7 = srcs[k + 7];
        float w0 = wgt[k],     w1 = wgt[k + 1], w2 = wgt[k + 2], w3 = wgt[k + 3];
        float w4 = wgt[k + 4], w5 = wgt[k + 5], w6 = wgt[k + 6], w7 = wgt[k + 7];
        float v0 = h[(size_t)s0 * F_HID + j];
        float v1 = h[(size_t)s1 * F_HID + j];
        float v2 = h[(size_t)s2 * F_HID + j];
        float v3 = h[(size_t)s3 * F_HID + j];
        float v4 = h[(size_t)s4 * F_HID + j];
        float v5 = h[(size_t)s5 * F_HID + j];
        float v6 = h[(size_t)s6 * F_HID + j];
        float v7 = h[(size_t)s7 * F_HID + j];
        acc0 = fmaf(v0, w0, acc0);
        acc1 = fmaf(v1, w1, acc1);
        acc2 = fmaf(v2, w2, acc2);
        acc3 = fmaf(v3, w3, acc3);
        acc0 = fmaf(v4, w4, acc0);
        acc1 = fmaf(v5, w5, acc1);
        acc2 = fmaf(v6, w6, acc2);
        acc3 = fmaf(v7, w7, acc3);
    }
    for (; k < k1; ++k)
        acc0 = fmaf(h[(size_t)srcs[k] * F_HID + j], wgt[k], acc0);
    h1[(size_t)node * F_HID + j] = fmaxf((acc0 + acc1) + (acc2 + acc3) + b1[j], 0.0f);
}

// ---------------- GEMM2: h1[N,64] @ W2[64,16] -> h2[N,16] ----------------
__global__ void k_gemm2(const float* __restrict__ h1, const float* __restrict__ W,
                        float* __restrict__ h2) {
    int t = blockIdx.x * blockDim.x + threadIdx.x;
    if (t < N_NODES * F_OUT) {
        int i = t >> 4, j = t & 15;
        float acc = 0.0f;
#pragma unroll
        for (int k = 0; k < F_HID; ++k)
            acc = fmaf(h1[(size_t)i * F_HID + k], W[k * F_OUT + j], acc);
        h2[t] = acc;
    }
}

// ---------------- CSR aggregation F=16: 4 groups x 16 feats, unroll-4 ---------
__global__ __launch_bounds__(256) void k_agg16_csr(const int* __restrict__ offs,
                                                   const int* __restrict__ srcs,
                                                   const float* __restrict__ wgt,
                                                   const float* __restrict__ dinv,
                                                   const float* __restrict__ h2,
                                                   const float* __restrict__ b2,
                                                   float* __restrict__ out) {
    int node = blockIdx.x * 4 + (threadIdx.x >> 6);
    int lane = threadIdx.x & 63;
    int eo = lane >> 4;
    int j  = lane & 15;
    if (node >= N_NODES) return;
    float dn = dinv[node];
    float acc0 = 0.0f, acc1 = 0.0f, acc2 = 0.0f, acc3 = 0.0f;
    int k0 = offs[node], k1 = offs[node + 1];
    int k = k0 + eo;
    for (; k + 12 < k1; k += 16) {
        int s0 = srcs[k], s1 = srcs[k + 4], s2 = srcs[k + 8], s3 = srcs[k + 12];
        float w0 = wgt[k], w1 = wgt[k + 4], w2 = wgt[k + 8], w3 = wgt[k + 12];
        float v0 = h2[(size_t)s0 * F_OUT + j];
        float v1 = h2[(size_t)s1 * F_OUT + j];
        float v2 = h2[(size_t)s2 * F_OUT + j];
        float v3 = h2[(size_t)s3 * F_OUT + j];
        acc0 = fmaf(v0, w0, acc0);
        acc1 = fmaf(v1, w1, acc1);
        acc2 = fmaf(v2, w2, acc2);
        acc3 = fmaf(v3, w3, acc3);
    }
    for (; k < k1; k += 4)
        acc0 = fmaf(h2[(size_t)srcs[k] * F_OUT + j], wgt[k], acc0);
    float acc = (acc0 + acc1) + (acc2 + acc3);
    acc += __shfl_xor(acc, 16);
    acc += __shfl_xor(acc, 32);
    if (eo == 0)
        out[(size_t)node * F_OUT + j] =
            acc + h2[(size_t)node * F_OUT + j] * dn * dn + b2[j];
}

extern "C" void kernel_launch(void* const* d_in, const int* in_sizes, int n_in,
                              void* d_out, int out_size, void* d_ws, size_t ws_size,
                              hipStream_t stream) {
    const float* x  = (const float*)d_in[0];
    const int*   ei = (const int*)d_in[1];
    const float* W1 = (const float*)d_in[2];
    const float* b1 = (const float*)d_in[3];
    const float* W2 = (const float*)d_in[4];
    const float* b2 = (const float*)d_in[5];
    float* out = (float*)d_out;

    const int* src = ei;
    const int* dst = ei + N_EDGES;

    int* wsi = (int*)d_ws;
    int* count      = wsi;                  // 50176 (consumed to 0 by k_fill)
    int* offs       = count + 50176;        // 50304
    int* bsum       = offs + 50304;         // 64
    int* src_sorted = bsum + 64;            // 800000
    float* w_sorted = (float*)(src_sorted + N_EDGES);    // 800000
    float* dinv = w_sorted + N_EDGES;                    // 50176
    float* h    = dinv + 50176;                          // N*64
    float* h1   = h + (size_t)N_NODES * F_HID;           // N*64
    float* h2   = h;                                     // alias: h dead after agg64

    (void)hipMemsetAsync(count, 0, N_NODES * sizeof(int), stream);

    // gemm1 + degree histogram in one launch (uniform across all blocks)
    k_mega<<<GRID, 512, 0, stream>>>(x, W1, dst, count, h);

    k_scanA<<<SCAN_NB, SCAN_B, 0, stream>>>(count, offs, bsum, dinv);
    k_scanBC<<<SCAN_NB, SCAN_B, 0, stream>>>(offs, bsum);
    k_fill<<<(N_EDGES + 255) / 256, 256, 0, stream>>>(src, dst, offs, count, dinv,
                                                      src_sorted, w_sorted);

    k_agg64_csr<<<(N_NODES + 3) / 4, 256, 0, stream>>>(offs, src_sorted, w_sorted,
                                                       dinv, h, b1, h1);
    k_gemm2<<<(N_NODES * F_OUT + 255) / 256, 256, 0, stream>>>(h1, W2, h2);
    k_agg16_csr<<<(N_NODES + 3) / 4, 256, 0, stream>>>(offs, src_sorted, w_sorted,
                                                       dinv, h2, b2, out);
}